// Round 8
// baseline (623.425 us; speedup 1.0000x reference)
//
#include <hip/hip_runtime.h>
#include <stdint.h>

#define B_    16
#define N_    65536
#define NPTS  (B_*N_)
#define NBK   11
#define NFEAT 259
#define NF    ((float)NPTS)

typedef float f32x4 __attribute__((ext_vector_type(4)));
typedef short s16x8 __attribute__((ext_vector_type(8)));

// ---- workspace float offsets ----
enum {
  OFF_YMINF = 16,      // 16
  OFF_YMAXF = 32,      // 16
  OFF_A1    = 64,      // 64
  OFF_C1    = 128,     // 64
  OFF_A2    = 192,     // 128
  OFF_C2    = 320,     // 128
  OFF_CX    = 448,     // 176
  OFF_CZ    = 624,     // 176
  OFF_A3    = 800,     // 256
  OFF_C3    = 1056,    // 256
  OFF_PSTR  = 16384,   // 512*16
  OFF_PBKT  = 24576,   // 512*36
  OFF_PSPA  = 43008,   // 512*8
  OFF_PH2   = 49152,   // 2048*256: sum[128], sq[128]   (bid*2+ptg)
  OFF_PH3   = 573440,  // 2048*512: sum[256], sq[256]
  OFF_PPOOL = 1622016  // 2048*512: max[256], sum[256]
};

// ---- helpers ----
__device__ __forceinline__ float wave_sum(float v){
  #pragma unroll
  for (int m=32;m>=1;m>>=1) v += __shfl_xor(v,m,64);
  return v;
}
__device__ __forceinline__ float wave_max(float v){
  #pragma unroll
  for (int m=32;m>=1;m>>=1) v = fmaxf(v,__shfl_xor(v,m,64));
  return v;
}
__device__ __forceinline__ float wave_min(float v){
  #pragma unroll
  for (int m=32;m>=1;m>>=1) v = fminf(v,__shfl_xor(v,m,64));
  return v;
}
__device__ __forceinline__ unsigned short bf16_bits(float f){
  unsigned u=__float_as_uint(f);
  u += 0x7FFFu + ((u>>16)&1u);
  return (unsigned short)(u>>16);
}
// packed RTNE f32x2 -> bf16x2 (no builtin on gfx950)
__device__ __forceinline__ unsigned cvt_pk_bf16(float lo, float hi){
  unsigned r;
  asm("v_cvt_pk_bf16_f32 %0, %1, %2" : "=v"(r) : "v"(lo), "v"(hi));
  return r;
}

// ---- pass A: x colsums + X^T X + per-batch y min/max -> per-block partials ----
__global__ __launch_bounds__(256) void k_stream0(const float* __restrict__ x,
                                                 float* __restrict__ ws){
  __shared__ float red[4][12];
  const int t=threadIdx.x, l=t&63, w=t>>6;
  const int bid=blockIdx.x;
  const float4* xv=(const float4*)(x + (size_t)bid*2048*3);
  float s0=0,s1=0,s2=0,q00=0,q01=0,q02=0,q11=0,q12=0,q22=0;
  float ymn=3.4e38f, ymx=-3.4e38f;
  #pragma unroll
  for (int i=0;i<2;i++){
    const int vi=(i*256+t)*3;
    const float4 a=xv[vi], b4=xv[vi+1], c=xv[vi+2];
    float X[4]={a.x,a.w,b4.z,c.y};
    float Y[4]={a.y,b4.x,b4.w,c.z};
    float Z[4]={a.z,b4.y,c.x,c.w};
    #pragma unroll
    for (int p=0;p<4;p++){
      s0+=X[p]; s1+=Y[p]; s2+=Z[p];
      q00=fmaf(X[p],X[p],q00); q01=fmaf(X[p],Y[p],q01); q02=fmaf(X[p],Z[p],q02);
      q11=fmaf(Y[p],Y[p],q11); q12=fmaf(Y[p],Z[p],q12); q22=fmaf(Z[p],Z[p],q22);
      ymn=fminf(ymn,Y[p]); ymx=fmaxf(ymx,Y[p]);
    }
  }
  s0=wave_sum(s0); s1=wave_sum(s1); s2=wave_sum(s2);
  q00=wave_sum(q00); q01=wave_sum(q01); q02=wave_sum(q02);
  q11=wave_sum(q11); q12=wave_sum(q12); q22=wave_sum(q22);
  ymn=wave_min(ymn); ymx=wave_max(ymx);
  if (l==0){
    red[w][0]=s0; red[w][1]=s1; red[w][2]=s2;
    red[w][3]=q00; red[w][4]=q01; red[w][5]=q02;
    red[w][6]=q11; red[w][7]=q12; red[w][8]=q22;
    red[w][9]=ymn; red[w][10]=ymx;
  }
  __syncthreads();
  if (t<11){
    const float v0=red[0][t],v1=red[1][t],v2=red[2][t],v3=red[3][t];
    float r;
    if (t==9)       r=fminf(fminf(v0,v1),fminf(v2,v3));
    else if (t==10) r=fmaxf(fmaxf(v0,v1),fmaxf(v2,v3));
    else            r=v0+v1+v2+v3;
    ws[OFF_PSTR+bid*16+t]=r;
  }
}

// ---- finA ----
__global__ void k_finA(const float* __restrict__ w1, const float* __restrict__ b1,
                       const float* __restrict__ gm, const float* __restrict__ bt,
                       float* __restrict__ ws){
  __shared__ float sums[9];
  const int t=threadIdx.x;
  if (t<9){
    float s=0.f;
    #pragma unroll 8
    for (int blk=0;blk<512;blk++) s+=ws[OFF_PSTR+blk*16+t];
    sums[t]=s;
  }
  if (t>=32&&t<48){
    const int b=t-32; float m=3.4e38f;
    #pragma unroll 8
    for (int blk=0;blk<32;blk++) m=fminf(m,ws[OFF_PSTR+(b*32+blk)*16+9]);
    ws[OFF_YMINF+b]=m;
  }
  if (t>=48&&t<64){
    const int b=t-48; float m=-3.4e38f;
    #pragma unroll 8
    for (int blk=0;blk<32;blk++) m=fmaxf(m,ws[OFF_PSTR+(b*32+blk)*16+10]);
    ws[OFF_YMAXF+b]=m;
  }
  __syncthreads();
  if (t<64){
    const float i_n=1.f/NF;
    const float w0=w1[t], wa=w1[64+t], wb=w1[128+t];
    const float ms=(w0*sums[0]+wa*sums[1]+wb*sums[2])*i_n;
    const float es=(w0*w0*sums[3]+wa*wa*sums[6]+wb*wb*sums[8]
                   +2.f*(w0*wa*sums[4]+w0*wb*sums[5]+wa*wb*sums[7]))*i_n;
    const float var=es-ms*ms;
    const float a=gm[t]/sqrtf(var+1e-5f);
    ws[OFF_A1+t]=a; ws[OFF_C1+t]=bt[t]-(ms+b1[t])*a;
  }
}

// ---- bucket segment sums -> per-block partials ----
__global__ __launch_bounds__(256) void k_bucket(const float* __restrict__ x,
                                                float* __restrict__ ws){
  __shared__ float red[4][12];
  const int t=threadIdx.x, l=t&63, w=t>>6;
  const int bid=blockIdx.x, b=bid>>5;
  const float ymn=ws[OFF_YMINF+b], ymx=ws[OFF_YMAXF+b];
  const float4* xv=(const float4*)(x + (size_t)bid*2048*3);
  float sxl[NBK], szl[NBK], cntl[NBK];
  #pragma unroll
  for (int k=0;k<NBK;k++){ sxl[k]=0.f; szl[k]=0.f; cntl[k]=0.f; }
  #pragma unroll
  for (int i=0;i<2;i++){
    const int vi=(i*256+t)*3;
    const float4 a=xv[vi], b4=xv[vi+1], c=xv[vi+2];
    float X[4]={a.x,a.w,b4.z,c.y};
    float Y[4]={a.y,b4.x,b4.w,c.z};
    float Z[4]={a.z,b4.y,c.x,c.w};
    #pragma unroll
    for (int p=0;p<4;p++){
      const float yn=(Y[p]-ymn)/(ymx-ymn+1e-6f);
      int bk=(int)(yn*10.f); bk = bk<0?0:(bk>10?10:bk);
      #pragma unroll
      for (int k=0;k<NBK;k++){
        const bool m=(bk==k);
        sxl[k]+= m?X[p]:0.f; szl[k]+= m?Z[p]:0.f; cntl[k]+= m?1.f:0.f;
      }
    }
  }
  #pragma unroll
  for (int k=0;k<NBK;k++){
    const float s=wave_sum(sxl[k]);
    if (l==0) red[w][k]=s;
  }
  __syncthreads();
  if (t<NBK) ws[OFF_PBKT+bid*36+t]=red[0][t]+red[1][t]+red[2][t]+red[3][t];
  __syncthreads();
  #pragma unroll
  for (int k=0;k<NBK;k++){
    const float z=wave_sum(szl[k]);
    if (l==0) red[w][k]=z;
  }
  __syncthreads();
  if (t<NBK) ws[OFF_PBKT+bid*36+11+t]=red[0][t]+red[1][t]+red[2][t]+red[3][t];
  __syncthreads();
  #pragma unroll
  for (int k=0;k<NBK;k++){
    const float c=wave_sum(cntl[k]);
    if (l==0) red[w][k]=c;
  }
  __syncthreads();
  if (t<NBK) ws[OFF_PBKT+bid*36+22+t]=red[0][t]+red[1][t]+red[2][t]+red[3][t];
}

// ---- finB ----
__global__ void k_finB(const float* __restrict__ gm, const float* __restrict__ bt,
                       float* __restrict__ ws){
  __shared__ float acc[256];
  const int t=threadIdx.x;              // 256 threads
  {
    const int col=t&127, part=t>>7;
    float s=0.f;
    #pragma unroll 8
    for (int blk=0;blk<2048;blk++) s+=ws[OFF_PH2+blk*256+part*128+col];
    acc[t]=s;
  }
  __syncthreads();
  if (t<128){
    const float i_n=1.f/NF;
    const float m=acc[t]*i_n;
    const float v=acc[128+t]*i_n-m*m;
    const float a=gm[t]/sqrtf(v+1e-5f);
    ws[OFF_A2+t]=a; ws[OFF_C2+t]=bt[t]-m*a;
  }
  if (t<176){
    const int b=t/NBK, k=t-b*NBK;
    float sx=0.f, sz=0.f, cn=0.f;
    #pragma unroll 8
    for (int blk=0;blk<32;blk++){
      const int p=OFF_PBKT+(b*32+blk)*36;
      sx+=ws[p+k]; sz+=ws[p+11+k]; cn+=ws[p+22+k];
    }
    const float d=fmaxf(cn,1.f);
    ws[OFF_CX+t]=sx/d; ws[OFF_CZ+t]=sz/d;
  }
}

// ---- finC ----
__global__ void k_finC(const float* __restrict__ gm, const float* __restrict__ bt,
                       float* __restrict__ ws){
  __shared__ float acc[512];
  const int t=threadIdx.x;              // 512 threads
  {
    const int col=t&255, part=t>>8;
    float s=0.f;
    #pragma unroll 8
    for (int blk=0;blk<2048;blk++) s+=ws[OFF_PH3+blk*512+part*256+col];
    acc[t]=s;
  }
  __syncthreads();
  if (t<256){
    const float i_n=1.f/NF;
    const float m=acc[t]*i_n;
    const float v=acc[256+t]*i_n-m*m;
    const float a=gm[t]/sqrtf(v+1e-5f);
    ws[OFF_A3+t]=a; ws[OFF_C3+t]=bt[t]-m*a;
  }
}

// ---- spatial features -> per-block partials ----
__global__ __launch_bounds__(256) void k_spatial(const float* __restrict__ x,
                                                 float* __restrict__ ws){
  __shared__ float red[4][8];
  const int t=threadIdx.x, l=t&63, w=t>>6;
  const int bid=blockIdx.x, b=bid>>5;
  const float ymn=ws[OFF_YMINF+b], ymx=ws[OFF_YMAXF+b];
  const float4* xv=(const float4*)(x + (size_t)bid*2048*3);
  float mx[3]={-3.4e38f,-3.4e38f,-3.4e38f}, sm[3]={0.f,0.f,0.f};
  #pragma unroll
  for (int i=0;i<2;i++){
    const int vi=(i*256+t)*3;
    const float4 a=xv[vi], b4=xv[vi+1], c=xv[vi+2];
    float X[4]={a.x,a.w,b4.z,c.y};
    float Y[4]={a.y,b4.x,b4.w,c.z};
    float Z[4]={a.z,b4.y,c.x,c.w};
    #pragma unroll
    for (int p=0;p<4;p++){
      const float yn=(Y[p]-ymn)/(ymx-ymn+1e-6f);
      int bk=(int)(yn*10.f); bk = bk<0?0:(bk>10?10:bk);
      const float dx=X[p]-ws[OFF_CX+b*NBK+bk];
      const float dz=Z[p]-ws[OFF_CZ+b*NBK+bk];
      const float r=sqrtf(fmaf(dx,dx,dz*dz));
      const float sn=(r>0.f)?(dz/r):0.f;
      const float cs=(r>0.f)?(dx/r):1.f;
      mx[0]=fmaxf(mx[0],sn); sm[0]+=sn;
      mx[1]=fmaxf(mx[1],cs); sm[1]+=cs;
      mx[2]=fmaxf(mx[2],r);  sm[2]+=r;
    }
  }
  #pragma unroll
  for (int q=0;q<3;q++){
    const float m=wave_max(mx[q]);
    const float s=wave_sum(sm[q]);
    if (l==0){ red[w][q]=m; red[w][4+q]=s; }
  }
  __syncthreads();
  if (t<3)        ws[OFF_PSPA+bid*8+t]  =fmaxf(fmaxf(red[0][t],red[1][t]),fmaxf(red[2][t],red[3][t]));
  else if (t>=4&&t<7){
    const int q=t-4;
    ws[OFF_PSPA+bid*8+4+q]=red[0][4+q]+red[1][4+q]+red[2][4+q]+red[3][4+q];
  }
}

// ---- MFMA MLP pass: 8 waves = 2 pt-groups x 4 feat-groups, x-prefetch, cvt_pk ----
// MODE 0 = h2 stats, 1 = h3 stats, 2 = pool.  grid 1024, 8 iters of 128 pts.
template<int MODE>
__global__ __launch_bounds__(512,2) void k_mlp(
    const float* __restrict__ x,
    const float* __restrict__ w1, const float* __restrict__ b1,
    const float* __restrict__ w2, const float* __restrict__ b2,
    const float* __restrict__ w3, const float* __restrict__ b3,
    float* __restrict__ ws)
{
  __shared__ short g1t[128*72];    // [pt][feat64], 144B rows
  __shared__ short g2t[128*136];   // [pt][feat128], 272B rows
  const int t=threadIdx.x, w=t>>6, l=t&63, lg=l>>4, lr=l&15;
  const int bid=blockIdx.x, b=bid>>6, chunk=bid&63;
  const int ptg=w&1, fgrp=w>>1;
  char* g1c=(char*)g1t; char* g2c=(char*)g2t;

  // ---- layer1 folded weights: lane computes feats 8fg..8fg+7 for 2 pts
  const int fg=l&7, pj=(l>>3)&7;
  const float* a1=ws+OFF_A1; const float* c1=ws+OFF_C1;
  float w1f[3][8], b1f[8];
  #pragma unroll
  for (int i=0;i<8;i++){
    const int f=8*fg+i; const float a=a1[f];
    #pragma unroll
    for (int q=0;q<3;q++) w1f[q][i]=w1[q*64+f]*a;
    b1f[i]=b1[f]*a+c1[f];
  }

  // ---- layer2 A-frags (W2^T): wave owns f2-tiles 2*fgrp+j, j=0,1
  s16x8 w2f[2][2]; float b2v[2][4];
  #pragma unroll
  for (int j=0;j<2;j++){
    const int col2=(2*fgrp+j)*16+lr;
    const float sc2=(MODE==0)?1.f:ws[OFF_A2+col2];
    #pragma unroll
    for (int kt=0;kt<2;kt++)
      #pragma unroll
      for (int i=0;i<8;i++)
        w2f[j][kt][i]=(short)bf16_bits(w2[(kt*32+8*lg+i)*128+col2]*sc2);
    #pragma unroll
    for (int r=0;r<4;r++){
      const int f2=(2*fgrp+j)*16+4*lg+r;
      b2v[j][r]=(MODE==0)? b2[f2] : (ws[OFF_A2+f2]*b2[f2]+ws[OFF_C2+f2]);
    }
  }

  // ---- layer3 A-frags (W3^T): wave owns f3-tiles 4*fgrp+j, j=0..3
  s16x8 w3f[4][4]; float b3v[4][4];
  if (MODE!=0){
    #pragma unroll
    for (int j=0;j<4;j++){
      const int col3=(4*fgrp+j)*16+lr;
      const float sc3=(MODE==1)?1.f:ws[OFF_A3+col3];
      #pragma unroll
      for (int kt=0;kt<4;kt++)
        #pragma unroll
        for (int i=0;i<8;i++)
          w3f[j][kt][i]=(short)bf16_bits(w3[(kt*32+8*lg+i)*256+col3]*sc3);
      #pragma unroll
      for (int r=0;r<4;r++){
        const int f3=(4*fgrp+j)*16+4*lg+r;
        b3v[j][r]=(MODE==1)? b3[f3] : (ws[OFF_A3+f3]*b3[f3]+ws[OFF_C3+f3]);
      }
    }
  }

  float aS[4][4], aQ[4][4];
  #pragma unroll
  for (int j=0;j<4;j++)
    #pragma unroll
    for (int r=0;r<4;r++){ aS[j][r]=(MODE==2)?-3.4e38f:0.f; aQ[j][r]=0.f; }

  const int base=b*N_+chunk*1024;
  const int ptl=16*w+2*pj;             // this lane's first point in tile

  // prefetch iteration 0
  float c0[3], c1v[3], n0[3], n1[3];
  {
    const float* xp=&x[(size_t)(base+ptl)*3];
    #pragma unroll
    for (int q=0;q<3;q++){ c0[q]=xp[q]; c1v[q]=xp[3+q]; }
  }

  #pragma unroll 1
  for (int it=0; it<8; ++it){
    // ---- layer1: 8 feats x 2 pts per lane -> g1 (b128 each)
    #pragma unroll
    for (int s=0;s<2;s++){
      const float x0=s?c1v[0]:c0[0], x1v=s?c1v[1]:c0[1], x2=s?c1v[2]:c0[2];
      unsigned pk[4];
      #pragma unroll
      for (int i=0;i<4;i++){
        float v0=b1f[2*i], v1=b1f[2*i+1];
        v0=fmaf(x0,w1f[0][2*i],v0);  v1=fmaf(x0,w1f[0][2*i+1],v1);
        v0=fmaf(x1v,w1f[1][2*i],v0); v1=fmaf(x1v,w1f[1][2*i+1],v1);
        v0=fmaf(x2,w1f[2][2*i],v0);  v1=fmaf(x2,w1f[2][2*i+1],v1);
        pk[i]=cvt_pk_bf16(fmaxf(v0,0.f),fmaxf(v1,0.f));
      }
      *(int4*)(g1c + (ptl+s)*144 + fg*16) = make_int4(pk[0],pk[1],pk[2],pk[3]);
    }
    // ---- prefetch next iteration's x (hidden under the 2 phases below)
    if (it<7){
      const float* xp=&x[(size_t)(base+(it+1)*128+ptl)*3];
      #pragma unroll
      for (int q=0;q<3;q++){ n0[q]=xp[q]; n1[q]=xp[3+q]; }
    }
    __syncthreads();
    // ---- layer2: own pt-group (4 ptiles), own 2 f2-tiles; bias as C-in
    #pragma unroll
    for (int pt=0;pt<4;pt++){
      const int row=ptg*64+pt*16+lr;
      const s16x8 bf0=*(const s16x8*)(g1c + row*144 + lg*16);
      const s16x8 bf1=*(const s16x8*)(g1c + row*144 + 64 + lg*16);
      #pragma unroll
      for (int j=0;j<2;j++){
        f32x4 acc={b2v[j][0],b2v[j][1],b2v[j][2],b2v[j][3]};
        acc=__builtin_amdgcn_mfma_f32_16x16x32_bf16(w2f[j][0],bf0,acc,0,0,0);
        acc=__builtin_amdgcn_mfma_f32_16x16x32_bf16(w2f[j][1],bf1,acc,0,0,0);
        if (MODE==0){
          #pragma unroll
          for (int r=0;r<4;r++){ const float h=acc[r]; aS[j][r]+=h; aQ[j][r]=fmaf(h,h,aQ[j][r]); }
        } else {
          const unsigned lo=cvt_pk_bf16(fmaxf(acc[0],0.f),fmaxf(acc[1],0.f));
          const unsigned hi=cvt_pk_bf16(fmaxf(acc[2],0.f),fmaxf(acc[3],0.f));
          *(uint2*)(g2c + row*272 + fgrp*64 + j*32 + lg*8) = make_uint2(lo,hi);
        }
      }
    }
    __syncthreads();
    // ---- layer3: own pt-group, own 4 f3-tiles; bias as C-in
    if (MODE!=0){
      #pragma unroll 1
      for (int pt=0;pt<4;pt++){
        const int row=ptg*64+pt*16+lr;
        const s16x8 bf0=*(const s16x8*)(g2c + row*272 + lg*16);
        const s16x8 bf1=*(const s16x8*)(g2c + row*272 + 64 + lg*16);
        const s16x8 bf2=*(const s16x8*)(g2c + row*272 + 128 + lg*16);
        const s16x8 bf3=*(const s16x8*)(g2c + row*272 + 192 + lg*16);
        #pragma unroll
        for (int j=0;j<4;j++){
          f32x4 a3={b3v[j][0],b3v[j][1],b3v[j][2],b3v[j][3]};
          a3=__builtin_amdgcn_mfma_f32_16x16x32_bf16(w3f[j][0],bf0,a3,0,0,0);
          a3=__builtin_amdgcn_mfma_f32_16x16x32_bf16(w3f[j][1],bf1,a3,0,0,0);
          a3=__builtin_amdgcn_mfma_f32_16x16x32_bf16(w3f[j][2],bf2,a3,0,0,0);
          a3=__builtin_amdgcn_mfma_f32_16x16x32_bf16(w3f[j][3],bf3,a3,0,0,0);
          #pragma unroll
          for (int r=0;r<4;r++){
            if (MODE==1){
              const float h=a3[r]; aS[j][r]+=h; aQ[j][r]=fmaf(h,h,aQ[j][r]);
            } else {
              const float g=fmaxf(a3[r],0.f);
              aS[j][r]=fmaxf(aS[j][r],g); aQ[j][r]+=g;
            }
          }
        }
      }
    }
    #pragma unroll
    for (int q=0;q<3;q++){ c0[q]=n0[q]; c1v[q]=n1[q]; }
  }

  // ---- flush: reduce over lr (16-lane groups); partial slot = bid*2+ptg
  const int bid2=bid*2+ptg;
  if (MODE==0){
    #pragma unroll
    for (int j=0;j<2;j++)
      #pragma unroll
      for (int r=0;r<4;r++){
        float s=aS[j][r], q=aQ[j][r];
        #pragma unroll
        for (int m=1;m<16;m<<=1){ s+=__shfl_xor(s,m); q+=__shfl_xor(q,m); }
        if (lr==0){
          const int f2=(2*fgrp+j)*16+4*lg+r;
          ws[OFF_PH2+bid2*256+f2]    =s;
          ws[OFF_PH2+bid2*256+128+f2]=q;
        }
      }
  } else if (MODE==1){
    #pragma unroll
    for (int j=0;j<4;j++)
      #pragma unroll
      for (int r=0;r<4;r++){
        float s=aS[j][r], q=aQ[j][r];
        #pragma unroll
        for (int m=1;m<16;m<<=1){ s+=__shfl_xor(s,m); q+=__shfl_xor(q,m); }
        if (lr==0){
          const int f3=(4*fgrp+j)*16+4*lg+r;
          ws[OFF_PH3+bid2*512+f3]    =s;
          ws[OFF_PH3+bid2*512+256+f3]=q;
        }
      }
  } else {
    #pragma unroll
    for (int j=0;j<4;j++)
      #pragma unroll
      for (int r=0;r<4;r++){
        float mxv=aS[j][r], s=aQ[j][r];
        #pragma unroll
        for (int m=1;m<16;m<<=1){ mxv=fmaxf(mxv,__shfl_xor(mxv,m)); s+=__shfl_xor(s,m); }
        if (lr==0){
          const int f3=(4*fgrp+j)*16+4*lg+r;
          ws[OFF_PPOOL+bid2*512+f3]    =mxv;
          ws[OFF_PPOOL+bid2*512+256+f3]=s;
        }
      }
  }
}

// ---- final: reduce pool partials, feat_cat(518) @ wp + bp, LayerNorm ----
__global__ __launch_bounds__(256) void k_final(
    const float* __restrict__ wp, const float* __restrict__ bp,
    const float* __restrict__ gln, const float* __restrict__ bln,
    float* __restrict__ out, const float* __restrict__ ws)
{
  __shared__ float feat[518];
  __shared__ float red[256];
  const int b=blockIdx.x, t=threadIdx.x;
  {
    float fm=-3.4e38f, fs=0.f;
    #pragma unroll 4
    for (int blk=0;blk<128;blk++){
      const int p=OFF_PPOOL+(b*128+blk)*512;
      fm=fmaxf(fm,ws[p+t]);
      fs+=ws[p+256+t];
    }
    feat[t]=fm; feat[NFEAT+t]=fs*(1.f/65536.f);
  }
  if (t<3){
    float fm=-3.4e38f, fs=0.f;
    #pragma unroll 4
    for (int blk=0;blk<32;blk++){
      const int p=OFF_PSPA+(b*32+blk)*8;
      fm=fmaxf(fm,ws[p+t]);
      fs+=ws[p+4+t];
    }
    feat[256+t]=fm; feat[NFEAT+256+t]=fs*(1.f/65536.f);
  }
  __syncthreads();
  float o0=bp[t], o1=bp[t+256];
  #pragma unroll 4
  for (int i=0;i<518;i++){
    const float f=feat[i];
    o0=fmaf(f, wp[i*512+t],     o0);
    o1=fmaf(f, wp[i*512+t+256], o1);
  }
  red[t]=o0+o1; __syncthreads();
  for (int s=128;s>0;s>>=1){ if (t<s) red[t]+=red[t+s]; __syncthreads(); }
  const float mu=red[0]*(1.f/512.f);
  __syncthreads();
  const float d0=o0-mu, d1=o1-mu;
  red[t]=d0*d0+d1*d1; __syncthreads();
  for (int s=128;s>0;s>>=1){ if (t<s) red[t]+=red[t+s]; __syncthreads(); }
  const float var=red[0]*(1.f/512.f);
  const float rs=1.f/sqrtf(var+1e-5f);
  out[b*512+t]     = d0*rs*gln[t]    +bln[t];
  out[b*512+t+256] = d1*rs*gln[t+256]+bln[t+256];
}

extern "C" void kernel_launch(void* const* d_in, const int* in_sizes, int n_in,
                              void* d_out, int out_size, void* d_ws, size_t ws_size,
                              hipStream_t stream)
{
  const float* x  =(const float*)d_in[0];
  const float* w1 =(const float*)d_in[1];
  const float* b1 =(const float*)d_in[2];
  const float* gm1=(const float*)d_in[3];
  const float* be1=(const float*)d_in[4];
  const float* w2 =(const float*)d_in[5];
  const float* b2 =(const float*)d_in[6];
  const float* gm2=(const float*)d_in[7];
  const float* be2=(const float*)d_in[8];
  const float* w3 =(const float*)d_in[9];
  const float* b3 =(const float*)d_in[10];
  const float* gm3=(const float*)d_in[11];
  const float* be3=(const float*)d_in[12];
  const float* wp =(const float*)d_in[13];
  const float* bp =(const float*)d_in[14];
  const float* gln=(const float*)d_in[15];
  const float* bln=(const float*)d_in[16];
  float* ws=(float*)d_ws;
  float* out=(float*)d_out;

  k_stream0<<<dim3(512), dim3(256),0,stream>>>(x,ws);
  k_finA   <<<dim3(1),   dim3(256),0,stream>>>(w1,b1,gm1,be1,ws);
  k_bucket <<<dim3(512), dim3(256),0,stream>>>(x,ws);
  k_mlp<0> <<<dim3(1024),dim3(512),0,stream>>>(x,w1,b1,w2,b2,w3,b3,ws);
  k_finB   <<<dim3(1),   dim3(256),0,stream>>>(gm2,be2,ws);
  k_spatial<<<dim3(512), dim3(256),0,stream>>>(x,ws);
  k_mlp<1> <<<dim3(1024),dim3(512),0,stream>>>(x,w1,b1,w2,b2,w3,b3,ws);
  k_finC   <<<dim3(1),   dim3(512),0,stream>>>(gm3,be3,ws);
  k_mlp<2> <<<dim3(1024),dim3(512),0,stream>>>(x,w1,b1,w2,b2,w3,b3,ws);
  k_final  <<<dim3(16),  dim3(256),0,stream>>>(wp,bp,gln,bln,out,ws);
}

// Round 9
// 477.081 us; speedup vs baseline: 1.3067x; 1.3067x over previous
//
#include <hip/hip_runtime.h>
#include <stdint.h>

#define B_    16
#define N_    65536
#define NPTS  (B_*N_)
#define NBK   11
#define NFEAT 259
#define NF    ((float)NPTS)

typedef float f32x4 __attribute__((ext_vector_type(4)));
typedef short s16x8 __attribute__((ext_vector_type(8)));
union frag_u { s16x8 v; unsigned u[4]; };
union x24_u  { float4 v4[6]; float f[24]; };

// ---- workspace float offsets ----
enum {
  OFF_YMINF = 16,      // 16
  OFF_YMAXF = 32,      // 16
  OFF_A1    = 64,      // 64
  OFF_C1    = 128,     // 64
  OFF_A2    = 192,     // 128
  OFF_C2    = 320,     // 128
  OFF_CX    = 448,     // 176
  OFF_CZ    = 624,     // 176
  OFF_A3    = 800,     // 256
  OFF_C3    = 1056,    // 256
  OFF_GC    = 2048,    // 4096 compact G
  OFF_G1S   = 6144,    // 64 compact sum(g1)
  OFF_H3C   = 6400,    // 512 compact h3 sum|sq
  OFF_PSTR  = 16384,   // 512*16
  OFF_PBKT  = 24576,   // 512*36
  OFF_PSPA  = 43008,   // 512*8
  OFF_PG    = 49152,   // 4096 x 512  ([elem][block])
  OFF_PGS   = 2146304, // 64 x 512
  OFF_PH3   = 2179072, // 512 x 1024  ([col][slot])
  OFF_PPOOL = 2703360  // 16 x 512 x 64 ([b][col][slot])
};

// ---- helpers ----
__device__ __forceinline__ float wave_sum(float v){
  #pragma unroll
  for (int m=32;m>=1;m>>=1) v += __shfl_xor(v,m,64);
  return v;
}
__device__ __forceinline__ float wave_max(float v){
  #pragma unroll
  for (int m=32;m>=1;m>>=1) v = fmaxf(v,__shfl_xor(v,m,64));
  return v;
}
__device__ __forceinline__ float wave_min(float v){
  #pragma unroll
  for (int m=32;m>=1;m>>=1) v = fminf(v,__shfl_xor(v,m,64));
  return v;
}
__device__ __forceinline__ unsigned short bf16_bits(float f){
  unsigned u=__float_as_uint(f);
  u += 0x7FFFu + ((u>>16)&1u);
  return (unsigned short)(u>>16);
}
__device__ __forceinline__ unsigned cvt_pk_bf16(float lo, float hi){
  unsigned r;
  asm("v_cvt_pk_bf16_f32 %0, %1, %2" : "=v"(r) : "v"(lo), "v"(hi));
  return r;
}

// ---- pass A: x colsums + X^T X + per-batch y min/max ----
__global__ __launch_bounds__(256) void k_stream0(const float* __restrict__ x,
                                                 float* __restrict__ ws){
  __shared__ float red[4][12];
  const int t=threadIdx.x, l=t&63, w=t>>6;
  const int bid=blockIdx.x;
  const float4* xv=(const float4*)(x + (size_t)bid*2048*3);
  float s0=0,s1=0,s2=0,q00=0,q01=0,q02=0,q11=0,q12=0,q22=0;
  float ymn=3.4e38f, ymx=-3.4e38f;
  #pragma unroll
  for (int i=0;i<2;i++){
    const int vi=(i*256+t)*3;
    const float4 a=xv[vi], b4=xv[vi+1], c=xv[vi+2];
    float X[4]={a.x,a.w,b4.z,c.y};
    float Y[4]={a.y,b4.x,b4.w,c.z};
    float Z[4]={a.z,b4.y,c.x,c.w};
    #pragma unroll
    for (int p=0;p<4;p++){
      s0+=X[p]; s1+=Y[p]; s2+=Z[p];
      q00=fmaf(X[p],X[p],q00); q01=fmaf(X[p],Y[p],q01); q02=fmaf(X[p],Z[p],q02);
      q11=fmaf(Y[p],Y[p],q11); q12=fmaf(Y[p],Z[p],q12); q22=fmaf(Z[p],Z[p],q22);
      ymn=fminf(ymn,Y[p]); ymx=fmaxf(ymx,Y[p]);
    }
  }
  s0=wave_sum(s0); s1=wave_sum(s1); s2=wave_sum(s2);
  q00=wave_sum(q00); q01=wave_sum(q01); q02=wave_sum(q02);
  q11=wave_sum(q11); q12=wave_sum(q12); q22=wave_sum(q22);
  ymn=wave_min(ymn); ymx=wave_max(ymx);
  if (l==0){
    red[w][0]=s0; red[w][1]=s1; red[w][2]=s2;
    red[w][3]=q00; red[w][4]=q01; red[w][5]=q02;
    red[w][6]=q11; red[w][7]=q12; red[w][8]=q22;
    red[w][9]=ymn; red[w][10]=ymx;
  }
  __syncthreads();
  if (t<11){
    const float v0=red[0][t],v1=red[1][t],v2=red[2][t],v3=red[3][t];
    float r;
    if (t==9)       r=fminf(fminf(v0,v1),fminf(v2,v3));
    else if (t==10) r=fmaxf(fmaxf(v0,v1),fmaxf(v2,v3));
    else            r=v0+v1+v2+v3;
    ws[OFF_PSTR+bid*16+t]=r;
  }
}

// ---- finA: BN1 fold via quadratic form; y min/max ----
__global__ void k_finA(const float* __restrict__ w1, const float* __restrict__ b1,
                       const float* __restrict__ gm, const float* __restrict__ bt,
                       float* __restrict__ ws){
  __shared__ float sums[9];
  const int t=threadIdx.x;
  if (t<9){
    float s=0.f;
    #pragma unroll 8
    for (int blk=0;blk<512;blk++) s+=ws[OFF_PSTR+blk*16+t];
    sums[t]=s;
  }
  if (t>=32&&t<48){
    const int b=t-32; float m=3.4e38f;
    #pragma unroll 8
    for (int blk=0;blk<32;blk++) m=fminf(m,ws[OFF_PSTR+(b*32+blk)*16+9]);
    ws[OFF_YMINF+b]=m;
  }
  if (t>=48&&t<64){
    const int b=t-48; float m=-3.4e38f;
    #pragma unroll 8
    for (int blk=0;blk<32;blk++) m=fmaxf(m,ws[OFF_PSTR+(b*32+blk)*16+10]);
    ws[OFF_YMAXF+b]=m;
  }
  __syncthreads();
  if (t<64){
    const float i_n=1.f/NF;
    const float w0=w1[t], wa=w1[64+t], wb=w1[128+t];
    const float ms=(w0*sums[0]+wa*sums[1]+wb*sums[2])*i_n;
    const float es=(w0*w0*sums[3]+wa*wa*sums[6]+wb*wb*sums[8]
                   +2.f*(w0*wa*sums[4]+w0*wb*sums[5]+wa*wb*sums[7]))*i_n;
    const float var=es-ms*ms;
    const float a=gm[t]/sqrtf(var+1e-5f);
    ws[OFF_A1+t]=a; ws[OFF_C1+t]=bt[t]-(ms+b1[t])*a;
  }
}

// ---- bucket segment sums ----
__global__ __launch_bounds__(256) void k_bucket(const float* __restrict__ x,
                                                float* __restrict__ ws){
  __shared__ float red[4][12];
  const int t=threadIdx.x, l=t&63, w=t>>6;
  const int bid=blockIdx.x, b=bid>>5;
  const float ymn=ws[OFF_YMINF+b], ymx=ws[OFF_YMAXF+b];
  const float4* xv=(const float4*)(x + (size_t)bid*2048*3);
  float sxl[NBK], szl[NBK], cntl[NBK];
  #pragma unroll
  for (int k=0;k<NBK;k++){ sxl[k]=0.f; szl[k]=0.f; cntl[k]=0.f; }
  #pragma unroll
  for (int i=0;i<2;i++){
    const int vi=(i*256+t)*3;
    const float4 a=xv[vi], b4=xv[vi+1], c=xv[vi+2];
    float X[4]={a.x,a.w,b4.z,c.y};
    float Y[4]={a.y,b4.x,b4.w,c.z};
    float Z[4]={a.z,b4.y,c.x,c.w};
    #pragma unroll
    for (int p=0;p<4;p++){
      const float yn=(Y[p]-ymn)/(ymx-ymn+1e-6f);
      int bk=(int)(yn*10.f); bk = bk<0?0:(bk>10?10:bk);
      #pragma unroll
      for (int k=0;k<NBK;k++){
        const bool m=(bk==k);
        sxl[k]+= m?X[p]:0.f; szl[k]+= m?Z[p]:0.f; cntl[k]+= m?1.f:0.f;
      }
    }
  }
  #pragma unroll
  for (int k=0;k<NBK;k++){
    const float s=wave_sum(sxl[k]);
    if (l==0) red[w][k]=s;
  }
  __syncthreads();
  if (t<NBK) ws[OFF_PBKT+bid*36+t]=red[0][t]+red[1][t]+red[2][t]+red[3][t];
  __syncthreads();
  #pragma unroll
  for (int k=0;k<NBK;k++){
    const float z=wave_sum(szl[k]);
    if (l==0) red[w][k]=z;
  }
  __syncthreads();
  if (t<NBK) ws[OFF_PBKT+bid*36+11+t]=red[0][t]+red[1][t]+red[2][t]+red[3][t];
  __syncthreads();
  #pragma unroll
  for (int k=0;k<NBK;k++){
    const float c=wave_sum(cntl[k]);
    if (l==0) red[w][k]=c;
  }
  __syncthreads();
  if (t<NBK) ws[OFF_PBKT+bid*36+22+t]=red[0][t]+red[1][t]+red[2][t]+red[3][t];
}

// ---- spatial features ----
__global__ __launch_bounds__(256) void k_spatial(const float* __restrict__ x,
                                                 float* __restrict__ ws){
  __shared__ float red[4][8];
  const int t=threadIdx.x, l=t&63, w=t>>6;
  const int bid=blockIdx.x, b=bid>>5;
  const float ymn=ws[OFF_YMINF+b], ymx=ws[OFF_YMAXF+b];
  const float4* xv=(const float4*)(x + (size_t)bid*2048*3);
  float mx[3]={-3.4e38f,-3.4e38f,-3.4e38f}, sm[3]={0.f,0.f,0.f};
  #pragma unroll
  for (int i=0;i<2;i++){
    const int vi=(i*256+t)*3;
    const float4 a=xv[vi], b4=xv[vi+1], c=xv[vi+2];
    float X[4]={a.x,a.w,b4.z,c.y};
    float Y[4]={a.y,b4.x,b4.w,c.z};
    float Z[4]={a.z,b4.y,c.x,c.w};
    #pragma unroll
    for (int p=0;p<4;p++){
      const float yn=(Y[p]-ymn)/(ymx-ymn+1e-6f);
      int bk=(int)(yn*10.f); bk = bk<0?0:(bk>10?10:bk);
      const float dx=X[p]-ws[OFF_CX+b*NBK+bk];
      const float dz=Z[p]-ws[OFF_CZ+b*NBK+bk];
      const float r=sqrtf(fmaf(dx,dx,dz*dz));
      const float sn=(r>0.f)?(dz/r):0.f;
      const float cs=(r>0.f)?(dx/r):1.f;
      mx[0]=fmaxf(mx[0],sn); sm[0]+=sn;
      mx[1]=fmaxf(mx[1],cs); sm[1]+=cs;
      mx[2]=fmaxf(mx[2],r);  sm[2]+=r;
    }
  }
  #pragma unroll
  for (int q=0;q<3;q++){
    const float m=wave_max(mx[q]);
    const float s=wave_sum(sm[q]);
    if (l==0){ red[w][q]=m; red[w][4+q]=s; }
  }
  __syncthreads();
  if (t<3)        ws[OFF_PSPA+bid*8+t]  =fmaxf(fmaxf(red[0][t],red[1][t]),fmaxf(red[2][t],red[3][t]));
  else if (t>=4&&t<7){
    const int q=t-4;
    ws[OFF_PSPA+bid*8+4+q]=red[0][4+q]+red[1][4+q]+red[2][4+q]+red[3][4+q];
  }
}

// ---- k_gram: G = g1^T g1 (64x64) + sum(g1) via MFMA, zero LDS, zero barriers ----
__global__ __launch_bounds__(512,2) void k_gram(
    const float* __restrict__ x,
    const float* __restrict__ w1, const float* __restrict__ b1,
    float* __restrict__ ws)
{
  const int t=threadIdx.x, w=t>>6, l=t&63, lg=l>>4, lr=l&15;
  const int bid=blockIdx.x;
  const int ti=w>>1, tj0=(w&1)*2, tj1=tj0+1;
  const float* A1=ws+OFF_A1; const float* C1=ws+OFF_C1;
  float wA[4], wB0[4], wB1[4];
  {
    const int fA=16*ti+lr;  const float aA=A1[fA];
    wA[0]=w1[fA]*aA;  wA[1]=w1[64+fA]*aA;  wA[2]=w1[128+fA]*aA;  wA[3]=b1[fA]*aA+C1[fA];
    const int f0=16*tj0+lr; const float a0=A1[f0];
    wB0[0]=w1[f0]*a0; wB0[1]=w1[64+f0]*a0; wB0[2]=w1[128+f0]*a0; wB0[3]=b1[f0]*a0+C1[f0];
    const int f1=16*tj1+lr; const float a1=A1[f1];
    wB1[0]=w1[f1]*a1; wB1[1]=w1[64+f1]*a1; wB1[2]=w1[128+f1]*a1; wB1[3]=b1[f1]*a1+C1[f1];
  }
  f32x4 acc0={0.f,0.f,0.f,0.f}, acc1={0.f,0.f,0.f,0.f};
  float s1=0.f;
  const float* xb = x + (size_t)bid*2048*3;
  #pragma unroll 1
  for (int step=0; step<64; ++step){
    x24_u xa;
    const float4* xp=(const float4*)(xb + (step*32+8*lg)*3);
    #pragma unroll
    for (int i=0;i<6;i++) xa.v4[i]=xp[i];
    float gA[8],gB0[8],gB1[8];
    #pragma unroll
    for (int j=0;j<8;j++){
      const float X=xa.f[3*j], Y=xa.f[3*j+1], Z=xa.f[3*j+2];
      gA[j] =fmaxf(fmaf(X,wA[0], fmaf(Y,wA[1], fmaf(Z,wA[2], wA[3]))),0.f);
      gB0[j]=fmaxf(fmaf(X,wB0[0],fmaf(Y,wB0[1],fmaf(Z,wB0[2],wB0[3]))),0.f);
      gB1[j]=fmaxf(fmaf(X,wB1[0],fmaf(Y,wB1[1],fmaf(Z,wB1[2],wB1[3]))),0.f);
    }
    frag_u fA,f0,f1;
    #pragma unroll
    for (int m=0;m<4;m++){
      fA.u[m]=cvt_pk_bf16(gA[2*m],gA[2*m+1]);
      f0.u[m]=cvt_pk_bf16(gB0[2*m],gB0[2*m+1]);
      f1.u[m]=cvt_pk_bf16(gB1[2*m],gB1[2*m+1]);
    }
    acc0=__builtin_amdgcn_mfma_f32_16x16x32_bf16(fA.v,f0.v,acc0,0,0,0);
    acc1=__builtin_amdgcn_mfma_f32_16x16x32_bf16(fA.v,f1.v,acc1,0,0,0);
    if (!(w&1)){
      #pragma unroll
      for (int j=0;j<8;j++) s1+=gA[j];
    }
  }
  #pragma unroll
  for (int q=0;q<4;q++){
    ws[OFF_PG + (size_t)((16*ti+4*lg+q)*64 + 16*tj0+lr)*512 + bid]=acc0[q];
    ws[OFF_PG + (size_t)((16*ti+4*lg+q)*64 + 16*tj1+lr)*512 + bid]=acc1[q];
  }
  if (!(w&1)){
    s1+=__shfl_xor(s1,16); s1+=__shfl_xor(s1,32);
    if (l<16) ws[OFF_PGS + (16*ti+lr)*512 + bid]=s1;
  }
}

// ---- k_redG: reduce G partials (+g1 sums) -> compact ----
__global__ __launch_bounds__(256) void k_redG(float* __restrict__ ws){
  __shared__ float red[256];
  const int t=threadIdx.x, blk=blockIdx.x;
  if (blk<64){
    const int e=blk*64+(t>>2), q=t&3;
    float s=0.f;
    const float* p=ws+OFF_PG+(size_t)e*512+q*128;
    #pragma unroll 8
    for (int i=0;i<128;i++) s+=p[i];
    red[t]=s; __syncthreads();
    if (q==0) ws[OFF_GC+e]=red[t]+red[t+1]+red[t+2]+red[t+3];
  } else {
    const int f=t>>2, q=t&3;
    float s=0.f;
    const float* p=ws+OFF_PGS+(size_t)f*512+q*128;
    #pragma unroll 8
    for (int i=0;i<128;i++) s+=p[i];
    red[t]=s; __syncthreads();
    if (q==0) ws[OFF_G1S+f]=red[t]+red[t+1]+red[t+2]+red[t+3];
  }
}

// ---- k_finB2: BN2 fold from G (128 blocks) + bucket centers (block 128) ----
__global__ __launch_bounds__(256) void k_finB2(
    const float* __restrict__ w2, const float* __restrict__ b2,
    const float* __restrict__ gm, const float* __restrict__ bt,
    float* __restrict__ ws){
  __shared__ float red[256];
  __shared__ float red2[64];
  const int t=threadIdx.x, j=blockIdx.x;
  if (j<128){
    float acc=0.f;
    #pragma unroll
    for (int p=0;p<16;p++){
      const int idx=p*256+t;
      const int r=idx>>6, c=idx&63;
      acc += w2[r*128+j]*ws[OFF_GC+r*64+c]*w2[c*128+j];
    }
    red[t]=acc;
    if (t<64) red2[t]=w2[t*128+j]*ws[OFF_G1S+t];
    __syncthreads();
    for (int s=128;s>0;s>>=1){ if (t<s) red[t]+=red[t+s]; __syncthreads(); }
    if (t<32) red2[t]+=red2[t+32];
    __syncthreads();
    if (t==0){
      float sw=0.f;
      #pragma unroll
      for (int i=0;i<32;i++) sw+=red2[i];
      const float i_n=1.f/NF;
      const float bj=b2[j];
      const float m=sw*i_n+bj;
      const float e2=(red[0]+2.f*bj*sw)*i_n+bj*bj;
      const float var=e2-m*m;
      const float a=gm[j]/sqrtf(var+1e-5f);
      ws[OFF_A2+j]=a; ws[OFF_C2+j]=bt[j]-m*a;
    }
  } else {
    if (t<176){
      const int b=t/NBK, k=t-b*NBK;
      float sx=0.f, sz=0.f, cn=0.f;
      #pragma unroll 8
      for (int blk=0;blk<32;blk++){
        const int p=OFF_PBKT+(b*32+blk)*36;
        sx+=ws[p+k]; sz+=ws[p+11+k]; cn+=ws[p+22+k];
      }
      const float d=fmaxf(cn,1.f);
      ws[OFF_CX+t]=sx/d; ws[OFF_CZ+t]=sz/d;
    }
  }
}

// ---- k_mlp: MODE 1 = h3 stats, 2 = pool. One barrier/iter, reg-resident L1+L2 ----
// grid 512 x 512 thr; block = 2048 pts; 16 iters x 128 pts; g2 double-buffered
template<int MODE>
__global__ __launch_bounds__(512) void k_mlp(
    const float* __restrict__ x,
    const float* __restrict__ w1, const float* __restrict__ b1,
    const float* __restrict__ w2, const float* __restrict__ b2,
    const float* __restrict__ w3, const float* __restrict__ b3,
    float* __restrict__ ws)
{
  __shared__ float xs[2048*3];           // 24 KB
  __shared__ short g2t[2*128*136];       // 68 KB (272B rows, dbuf)
  const int t=threadIdx.x, w=t>>6, l=t&63, lg=l>>4, lr=l&15;
  const int bid=blockIdx.x;
  const int ptg=w&1, fgrp=w>>1;
  char* g2base=(char*)g2t;

  // stage x (coalesced float4)
  {
    const float4* xp=(const float4*)(x + (size_t)bid*2048*3);
    float4* xd=(float4*)xs;
    #pragma unroll
    for (int i=0;i<3;i++) xd[i*512+t]=xp[i*512+t];
  }

  // layer1 folded weights: feats kt*32+8lg+i
  const float* A1=ws+OFF_A1; const float* C1=ws+OFF_C1;
  float w1f[2][3][8], b1f[2][8];
  #pragma unroll
  for (int kt=0;kt<2;kt++)
    #pragma unroll
    for (int i=0;i<8;i++){
      const int f=kt*32+8*lg+i; const float a=A1[f];
      w1f[kt][0][i]=w1[f]*a; w1f[kt][1][i]=w1[64+f]*a; w1f[kt][2][i]=w1[128+f]*a;
      b1f[kt][i]=b1[f]*a+C1[f];
    }

  // layer2 A-frags (folded BN2): fgrp owns f2-tiles 2fgrp, 2fgrp+1
  s16x8 w2f[2][2]; float b2i[2][4];
  #pragma unroll
  for (int j=0;j<2;j++){
    const int col2=(2*fgrp+j)*16+lr;
    const float sc2=ws[OFF_A2+col2];
    #pragma unroll
    for (int kt=0;kt<2;kt++)
      #pragma unroll
      for (int i=0;i<8;i++)
        w2f[j][kt][i]=(short)bf16_bits(w2[(kt*32+8*lg+i)*128+col2]*sc2);
    #pragma unroll
    for (int r=0;r<4;r++){
      const int f2=(2*fgrp+j)*16+4*lg+r;
      b2i[j][r]=ws[OFF_A2+f2]*b2[f2]+ws[OFF_C2+f2];
    }
  }

  // layer3 A-frags: fgrp owns f3-tiles 4fgrp..4fgrp+3
  s16x8 w3f[4][4]; float b3i[4][4];
  #pragma unroll
  for (int j=0;j<4;j++){
    const int col3=(4*fgrp+j)*16+lr;
    const float sc3=(MODE==1)?1.f:ws[OFF_A3+col3];
    #pragma unroll
    for (int kt=0;kt<4;kt++)
      #pragma unroll
      for (int i=0;i<8;i++)
        w3f[j][kt][i]=(short)bf16_bits(w3[(kt*32+8*lg+i)*256+col3]*sc3);
    #pragma unroll
    for (int r=0;r<4;r++){
      const int f3=(4*fgrp+j)*16+4*lg+r;
      b3i[j][r]=(MODE==1)? b3[f3] : (ws[OFF_A3+f3]*b3[f3]+ws[OFF_C3+f3]);
    }
  }

  float aS[4][4], aQ[4][4];
  #pragma unroll
  for (int j=0;j<4;j++)
    #pragma unroll
    for (int r=0;r<4;r++){ aS[j][r]=(MODE==2)?-3.4e38f:0.f; aQ[j][r]=0.f; }

  __syncthreads();   // x staged

  int cur=0;
  #pragma unroll 1
  for (int it=0; it<16; ++it){
    char* g2cur=g2base + cur*(128*272);
    // ---- L1+L2 (register path): own ptg's 4 pt-tiles
    #pragma unroll
    for (int pt=0;pt<4;pt++){
      const int row=ptg*64+pt*16+lr;
      const int pidx=it*128+row;
      const float x0=xs[pidx*3+0], x1v=xs[pidx*3+1], x2=xs[pidx*3+2];
      frag_u bf[2];
      #pragma unroll
      for (int kt=0;kt<2;kt++){
        float h[8];
        #pragma unroll
        for (int i=0;i<8;i++){
          float v=b1f[kt][i];
          v=fmaf(x0,w1f[kt][0][i],v); v=fmaf(x1v,w1f[kt][1][i],v); v=fmaf(x2,w1f[kt][2][i],v);
          h[i]=fmaxf(v,0.f);
        }
        #pragma unroll
        for (int m=0;m<4;m++) bf[kt].u[m]=cvt_pk_bf16(h[2*m],h[2*m+1]);
      }
      #pragma unroll
      for (int j=0;j<2;j++){
        f32x4 acc={b2i[j][0],b2i[j][1],b2i[j][2],b2i[j][3]};
        acc=__builtin_amdgcn_mfma_f32_16x16x32_bf16(w2f[j][0],bf[0].v,acc,0,0,0);
        acc=__builtin_amdgcn_mfma_f32_16x16x32_bf16(w2f[j][1],bf[1].v,acc,0,0,0);
        const unsigned lo=cvt_pk_bf16(fmaxf(acc[0],0.f),fmaxf(acc[1],0.f));
        const unsigned hi=cvt_pk_bf16(fmaxf(acc[2],0.f),fmaxf(acc[3],0.f));
        *(uint2*)(g2cur + row*272 + fgrp*64 + j*32 + lg*8)=make_uint2(lo,hi);
      }
    }
    __syncthreads();   // the ONLY barrier per iteration
    // ---- L3: own ptg's 4 pt-tiles, own 4 f3-tiles
    #pragma unroll 1
    for (int pt=0;pt<4;pt++){
      const int row=ptg*64+pt*16+lr;
      const char* rp=g2cur + row*272;
      s16x8 bfr0=*(const s16x8*)(rp + lg*16);
      s16x8 bfr1=*(const s16x8*)(rp + 64 + lg*16);
      s16x8 bfr2=*(const s16x8*)(rp + 128 + lg*16);
      s16x8 bfr3=*(const s16x8*)(rp + 192 + lg*16);
      #pragma unroll
      for (int j=0;j<4;j++){
        f32x4 a3={b3i[j][0],b3i[j][1],b3i[j][2],b3i[j][3]};
        a3=__builtin_amdgcn_mfma_f32_16x16x32_bf16(w3f[j][0],bfr0,a3,0,0,0);
        a3=__builtin_amdgcn_mfma_f32_16x16x32_bf16(w3f[j][1],bfr1,a3,0,0,0);
        a3=__builtin_amdgcn_mfma_f32_16x16x32_bf16(w3f[j][2],bfr2,a3,0,0,0);
        a3=__builtin_amdgcn_mfma_f32_16x16x32_bf16(w3f[j][3],bfr3,a3,0,0,0);
        #pragma unroll
        for (int r=0;r<4;r++){
          if (MODE==1){
            const float h=a3[r]; aS[j][r]+=h; aQ[j][r]=fmaf(h,h,aQ[j][r]);
          } else {
            const float g=fmaxf(a3[r],0.f);
            aS[j][r]=fmaxf(aS[j][r],g); aQ[j][r]+=g;
          }
        }
      }
    }
    cur^=1;
  }

  // ---- flush: reduce over lr; [col][slot] layout
  const int slot=bid*2+ptg;
  #pragma unroll
  for (int j=0;j<4;j++)
    #pragma unroll
    for (int r=0;r<4;r++){
      const int f3=(4*fgrp+j)*16+4*lg+r;
      if (MODE==1){
        float s=aS[j][r], q=aQ[j][r];
        #pragma unroll
        for (int m=1;m<16;m<<=1){ s+=__shfl_xor(s,m); q+=__shfl_xor(q,m); }
        if (lr==0){
          ws[OFF_PH3 + (size_t)f3*1024 + slot]=s;
          ws[OFF_PH3 + (size_t)(256+f3)*1024 + slot]=q;
        }
      } else {
        float mxv=aS[j][r], s=aQ[j][r];
        #pragma unroll
        for (int m=1;m<16;m<<=1){ mxv=fmaxf(mxv,__shfl_xor(mxv,m)); s+=__shfl_xor(s,m); }
        if (lr==0){
          const int b=bid>>5, chunk=bid&31;
          ws[OFF_PPOOL + (size_t)b*512*64 + (size_t)f3*64 + chunk*2+ptg]=mxv;
          ws[OFF_PPOOL + (size_t)b*512*64 + (size_t)(256+f3)*64 + chunk*2+ptg]=s;
        }
      }
    }
}

// ---- k_redH3: [col][1024 slots] -> compact ----
__global__ __launch_bounds__(256) void k_redH3(float* __restrict__ ws){
  __shared__ float red[256];
  const int t=threadIdx.x, blk=blockIdx.x;
  const int col=blk*16+(t>>4), part=t&15;
  float s=0.f;
  const float* p=ws+OFF_PH3+(size_t)col*1024+part*64;
  #pragma unroll 8
  for (int i=0;i<64;i++) s+=p[i];
  red[t]=s; __syncthreads();
  if (part==0){
    float r=0.f;
    #pragma unroll
    for (int i=0;i<16;i++) r+=red[(t&~15)+i];
    ws[OFF_H3C+col]=r;
  }
}

// ---- finC: BN3 fold from compact ----
__global__ void k_finC(const float* __restrict__ gm, const float* __restrict__ bt,
                       float* __restrict__ ws){
  const int t=threadIdx.x;
  if (t<256){
    const float i_n=1.f/NF;
    const float m=ws[OFF_H3C+t]*i_n;
    const float v=ws[OFF_H3C+256+t]*i_n-m*m;
    const float a=gm[t]/sqrtf(v+1e-5f);
    ws[OFF_A3+t]=a; ws[OFF_C3+t]=bt[t]-m*a;
  }
}

// ---- final: reduce pool, feat_cat(518) @ wp + bp, LayerNorm ----
__global__ __launch_bounds__(256) void k_final(
    const float* __restrict__ wp, const float* __restrict__ bp,
    const float* __restrict__ gln, const float* __restrict__ bln,
    float* __restrict__ out, const float* __restrict__ ws)
{
  __shared__ float feat[518];
  __shared__ float red[256];
  const int b=blockIdx.x, t=threadIdx.x;
  {
    float fm=-3.4e38f, fs=0.f;
    const float* pm=ws+OFF_PPOOL+(size_t)b*512*64+(size_t)t*64;
    const float* psu=ws+OFF_PPOOL+(size_t)b*512*64+(size_t)(256+t)*64;
    #pragma unroll 8
    for (int s=0;s<64;s++){ fm=fmaxf(fm,pm[s]); fs+=psu[s]; }
    feat[t]=fm; feat[NFEAT+t]=fs*(1.f/65536.f);
  }
  if (t<3){
    float fm=-3.4e38f, fs=0.f;
    #pragma unroll 4
    for (int blk=0;blk<32;blk++){
      const int p=OFF_PSPA+(b*32+blk)*8;
      fm=fmaxf(fm,ws[p+t]);
      fs+=ws[p+4+t];
    }
    feat[256+t]=fm; feat[NFEAT+256+t]=fs*(1.f/65536.f);
  }
  __syncthreads();
  float o0=bp[t], o1=bp[t+256];
  #pragma unroll 4
  for (int i=0;i<518;i++){
    const float f=feat[i];
    o0=fmaf(f, wp[i*512+t],     o0);
    o1=fmaf(f, wp[i*512+t+256], o1);
  }
  red[t]=o0+o1; __syncthreads();
  for (int s=128;s>0;s>>=1){ if (t<s) red[t]+=red[t+s]; __syncthreads(); }
  const float mu=red[0]*(1.f/512.f);
  __syncthreads();
  const float d0=o0-mu, d1=o1-mu;
  red[t]=d0*d0+d1*d1; __syncthreads();
  for (int s=128;s>0;s>>=1){ if (t<s) red[t]+=red[t+s]; __syncthreads(); }
  const float var=red[0]*(1.f/512.f);
  const float rs=1.f/sqrtf(var+1e-5f);
  out[b*512+t]     = d0*rs*gln[t]    +bln[t];
  out[b*512+t+256] = d1*rs*gln[t+256]+bln[t+256];
}

extern "C" void kernel_launch(void* const* d_in, const int* in_sizes, int n_in,
                              void* d_out, int out_size, void* d_ws, size_t ws_size,
                              hipStream_t stream)
{
  const float* x  =(const float*)d_in[0];
  const float* w1 =(const float*)d_in[1];
  const float* b1 =(const float*)d_in[2];
  const float* gm1=(const float*)d_in[3];
  const float* be1=(const float*)d_in[4];
  const float* w2 =(const float*)d_in[5];
  const float* b2 =(const float*)d_in[6];
  const float* gm2=(const float*)d_in[7];
  const float* be2=(const float*)d_in[8];
  const float* w3 =(const float*)d_in[9];
  const float* b3 =(const float*)d_in[10];
  const float* gm3=(const float*)d_in[11];
  const float* be3=(const float*)d_in[12];
  const float* wp =(const float*)d_in[13];
  const float* bp =(const float*)d_in[14];
  const float* gln=(const float*)d_in[15];
  const float* bln=(const float*)d_in[16];
  float* ws=(float*)d_ws;
  float* out=(float*)d_out;

  k_stream0<<<dim3(512),dim3(256),0,stream>>>(x,ws);
  k_finA   <<<dim3(1),  dim3(256),0,stream>>>(w1,b1,gm1,be1,ws);
  k_bucket <<<dim3(512),dim3(256),0,stream>>>(x,ws);
  k_gram   <<<dim3(512),dim3(512),0,stream>>>(x,w1,b1,ws);
  k_redG   <<<dim3(65), dim3(256),0,stream>>>(ws);
  k_finB2  <<<dim3(129),dim3(256),0,stream>>>(w2,b2,gm2,be2,ws);
  k_spatial<<<dim3(512),dim3(256),0,stream>>>(x,ws);
  k_mlp<1> <<<dim3(512),dim3(512),0,stream>>>(x,w1,b1,w2,b2,w3,b3,ws);
  k_redH3  <<<dim3(32), dim3(256),0,stream>>>(ws);
  k_finC   <<<dim3(1),  dim3(256),0,stream>>>(gm3,be3,ws);
  k_mlp<2> <<<dim3(512),dim3(512),0,stream>>>(x,w1,b1,w2,b2,w3,b3,ws);
  k_final  <<<dim3(16), dim3(256),0,stream>>>(wp,bp,gln,bln,out,ws);
}

// Round 10
// 446.912 us; speedup vs baseline: 1.3950x; 1.0675x over previous
//
#include <hip/hip_runtime.h>
#include <stdint.h>

#define B_    16
#define N_    65536
#define NPTS  (B_*N_)
#define NBK   11
#define NFEAT 259
#define NF    ((float)NPTS)

typedef float f32x4 __attribute__((ext_vector_type(4)));
typedef short s16x8 __attribute__((ext_vector_type(8)));
union frag_u { s16x8 v; unsigned u[4]; };
union x24_u  { float4 v4[6]; float f[24]; };

// ---- workspace float offsets ----
enum {
  OFF_YMINF = 16,      // 16
  OFF_YMAXF = 32,      // 16
  OFF_A1    = 64,      // 64
  OFF_C1    = 128,     // 64
  OFF_A2    = 192,     // 128
  OFF_C2    = 320,     // 128
  OFF_CX    = 448,     // 176
  OFF_CZ    = 624,     // 176
  OFF_A3    = 800,     // 256
  OFF_C3    = 1056,    // 256
  OFF_GC    = 2048,    // 4096 compact G
  OFF_G1S   = 6144,    // 64 compact sum(g1)
  OFF_H3C   = 6400,    // 512 compact h3 sum|sq
  OFF_PSTR  = 16384,   // 512*16
  OFF_PBKT  = 24576,   // 512*36
  OFF_PSPA  = 43008,   // 512*8
  OFF_PG    = 49152,   // 4096 x 512  ([elem][block])
  OFF_PGS   = 2146304, // 64 x 512
  OFF_PH3   = 2179072, // 512 x 2048  ([col][slot])
  OFF_PPOOL = 3227648  // 16 x 512 x 128 ([b][col][slot])
};

// ---- helpers ----
__device__ __forceinline__ float wave_sum(float v){
  #pragma unroll
  for (int m=32;m>=1;m>>=1) v += __shfl_xor(v,m,64);
  return v;
}
__device__ __forceinline__ float wave_max(float v){
  #pragma unroll
  for (int m=32;m>=1;m>>=1) v = fmaxf(v,__shfl_xor(v,m,64));
  return v;
}
__device__ __forceinline__ float wave_min(float v){
  #pragma unroll
  for (int m=32;m>=1;m>>=1) v = fminf(v,__shfl_xor(v,m,64));
  return v;
}
__device__ __forceinline__ unsigned short bf16_bits(float f){
  unsigned u=__float_as_uint(f);
  u += 0x7FFFu + ((u>>16)&1u);
  return (unsigned short)(u>>16);
}
__device__ __forceinline__ unsigned cvt_pk_bf16(float lo, float hi){
  unsigned r;
  asm("v_cvt_pk_bf16_f32 %0, %1, %2" : "=v"(r) : "v"(lo), "v"(hi));
  return r;
}

// ---- pass A: x colsums + X^T X + per-batch y min/max ----
__global__ __launch_bounds__(256) void k_stream0(const float* __restrict__ x,
                                                 float* __restrict__ ws){
  __shared__ float red[4][12];
  const int t=threadIdx.x, l=t&63, w=t>>6;
  const int bid=blockIdx.x;
  const float4* xv=(const float4*)(x + (size_t)bid*2048*3);
  float s0=0,s1=0,s2=0,q00=0,q01=0,q02=0,q11=0,q12=0,q22=0;
  float ymn=3.4e38f, ymx=-3.4e38f;
  #pragma unroll
  for (int i=0;i<2;i++){
    const int vi=(i*256+t)*3;
    const float4 a=xv[vi], b4=xv[vi+1], c=xv[vi+2];
    float X[4]={a.x,a.w,b4.z,c.y};
    float Y[4]={a.y,b4.x,b4.w,c.z};
    float Z[4]={a.z,b4.y,c.x,c.w};
    #pragma unroll
    for (int p=0;p<4;p++){
      s0+=X[p]; s1+=Y[p]; s2+=Z[p];
      q00=fmaf(X[p],X[p],q00); q01=fmaf(X[p],Y[p],q01); q02=fmaf(X[p],Z[p],q02);
      q11=fmaf(Y[p],Y[p],q11); q12=fmaf(Y[p],Z[p],q12); q22=fmaf(Z[p],Z[p],q22);
      ymn=fminf(ymn,Y[p]); ymx=fmaxf(ymx,Y[p]);
    }
  }
  s0=wave_sum(s0); s1=wave_sum(s1); s2=wave_sum(s2);
  q00=wave_sum(q00); q01=wave_sum(q01); q02=wave_sum(q02);
  q11=wave_sum(q11); q12=wave_sum(q12); q22=wave_sum(q22);
  ymn=wave_min(ymn); ymx=wave_max(ymx);
  if (l==0){
    red[w][0]=s0; red[w][1]=s1; red[w][2]=s2;
    red[w][3]=q00; red[w][4]=q01; red[w][5]=q02;
    red[w][6]=q11; red[w][7]=q12; red[w][8]=q22;
    red[w][9]=ymn; red[w][10]=ymx;
  }
  __syncthreads();
  if (t<11){
    const float v0=red[0][t],v1=red[1][t],v2=red[2][t],v3=red[3][t];
    float r;
    if (t==9)       r=fminf(fminf(v0,v1),fminf(v2,v3));
    else if (t==10) r=fmaxf(fmaxf(v0,v1),fmaxf(v2,v3));
    else            r=v0+v1+v2+v3;
    ws[OFF_PSTR+bid*16+t]=r;
  }
}

// ---- finA: BN1 fold via quadratic form; y min/max ----
__global__ void k_finA(const float* __restrict__ w1, const float* __restrict__ b1,
                       const float* __restrict__ gm, const float* __restrict__ bt,
                       float* __restrict__ ws){
  __shared__ float sums[9];
  const int t=threadIdx.x;
  if (t<9){
    float s=0.f;
    #pragma unroll 8
    for (int blk=0;blk<512;blk++) s+=ws[OFF_PSTR+blk*16+t];
    sums[t]=s;
  }
  if (t>=32&&t<48){
    const int b=t-32; float m=3.4e38f;
    #pragma unroll 8
    for (int blk=0;blk<32;blk++) m=fminf(m,ws[OFF_PSTR+(b*32+blk)*16+9]);
    ws[OFF_YMINF+b]=m;
  }
  if (t>=48&&t<64){
    const int b=t-48; float m=-3.4e38f;
    #pragma unroll 8
    for (int blk=0;blk<32;blk++) m=fmaxf(m,ws[OFF_PSTR+(b*32+blk)*16+10]);
    ws[OFF_YMAXF+b]=m;
  }
  __syncthreads();
  if (t<64){
    const float i_n=1.f/NF;
    const float w0=w1[t], wa=w1[64+t], wb=w1[128+t];
    const float ms=(w0*sums[0]+wa*sums[1]+wb*sums[2])*i_n;
    const float es=(w0*w0*sums[3]+wa*wa*sums[6]+wb*wb*sums[8]
                   +2.f*(w0*wa*sums[4]+w0*wb*sums[5]+wa*wb*sums[7]))*i_n;
    const float var=es-ms*ms;
    const float a=gm[t]/sqrtf(var+1e-5f);
    ws[OFF_A1+t]=a; ws[OFF_C1+t]=bt[t]-(ms+b1[t])*a;
  }
}

// ---- bucket segment sums ----
__global__ __launch_bounds__(256) void k_bucket(const float* __restrict__ x,
                                                float* __restrict__ ws){
  __shared__ float red[4][12];
  const int t=threadIdx.x, l=t&63, w=t>>6;
  const int bid=blockIdx.x, b=bid>>5;
  const float ymn=ws[OFF_YMINF+b], ymx=ws[OFF_YMAXF+b];
  const float4* xv=(const float4*)(x + (size_t)bid*2048*3);
  float sxl[NBK], szl[NBK], cntl[NBK];
  #pragma unroll
  for (int k=0;k<NBK;k++){ sxl[k]=0.f; szl[k]=0.f; cntl[k]=0.f; }
  #pragma unroll
  for (int i=0;i<2;i++){
    const int vi=(i*256+t)*3;
    const float4 a=xv[vi], b4=xv[vi+1], c=xv[vi+2];
    float X[4]={a.x,a.w,b4.z,c.y};
    float Y[4]={a.y,b4.x,b4.w,c.z};
    float Z[4]={a.z,b4.y,c.x,c.w};
    #pragma unroll
    for (int p=0;p<4;p++){
      const float yn=(Y[p]-ymn)/(ymx-ymn+1e-6f);
      int bk=(int)(yn*10.f); bk = bk<0?0:(bk>10?10:bk);
      #pragma unroll
      for (int k=0;k<NBK;k++){
        const bool m=(bk==k);
        sxl[k]+= m?X[p]:0.f; szl[k]+= m?Z[p]:0.f; cntl[k]+= m?1.f:0.f;
      }
    }
  }
  #pragma unroll
  for (int k=0;k<NBK;k++){
    const float s=wave_sum(sxl[k]);
    if (l==0) red[w][k]=s;
  }
  __syncthreads();
  if (t<NBK) ws[OFF_PBKT+bid*36+t]=red[0][t]+red[1][t]+red[2][t]+red[3][t];
  __syncthreads();
  #pragma unroll
  for (int k=0;k<NBK;k++){
    const float z=wave_sum(szl[k]);
    if (l==0) red[w][k]=z;
  }
  __syncthreads();
  if (t<NBK) ws[OFF_PBKT+bid*36+11+t]=red[0][t]+red[1][t]+red[2][t]+red[3][t];
  __syncthreads();
  #pragma unroll
  for (int k=0;k<NBK;k++){
    const float c=wave_sum(cntl[k]);
    if (l==0) red[w][k]=c;
  }
  __syncthreads();
  if (t<NBK) ws[OFF_PBKT+bid*36+22+t]=red[0][t]+red[1][t]+red[2][t]+red[3][t];
}

// ---- spatial features ----
__global__ __launch_bounds__(256) void k_spatial(const float* __restrict__ x,
                                                 float* __restrict__ ws){
  __shared__ float red[4][8];
  const int t=threadIdx.x, l=t&63, w=t>>6;
  const int bid=blockIdx.x, b=bid>>5;
  const float ymn=ws[OFF_YMINF+b], ymx=ws[OFF_YMAXF+b];
  const float4* xv=(const float4*)(x + (size_t)bid*2048*3);
  float mx[3]={-3.4e38f,-3.4e38f,-3.4e38f}, sm[3]={0.f,0.f,0.f};
  #pragma unroll
  for (int i=0;i<2;i++){
    const int vi=(i*256+t)*3;
    const float4 a=xv[vi], b4=xv[vi+1], c=xv[vi+2];
    float X[4]={a.x,a.w,b4.z,c.y};
    float Y[4]={a.y,b4.x,b4.w,c.z};
    float Z[4]={a.z,b4.y,c.x,c.w};
    #pragma unroll
    for (int p=0;p<4;p++){
      const float yn=(Y[p]-ymn)/(ymx-ymn+1e-6f);
      int bk=(int)(yn*10.f); bk = bk<0?0:(bk>10?10:bk);
      const float dx=X[p]-ws[OFF_CX+b*NBK+bk];
      const float dz=Z[p]-ws[OFF_CZ+b*NBK+bk];
      const float r=sqrtf(fmaf(dx,dx,dz*dz));
      const float sn=(r>0.f)?(dz/r):0.f;
      const float cs=(r>0.f)?(dx/r):1.f;
      mx[0]=fmaxf(mx[0],sn); sm[0]+=sn;
      mx[1]=fmaxf(mx[1],cs); sm[1]+=cs;
      mx[2]=fmaxf(mx[2],r);  sm[2]+=r;
    }
  }
  #pragma unroll
  for (int q=0;q<3;q++){
    const float m=wave_max(mx[q]);
    const float s=wave_sum(sm[q]);
    if (l==0){ red[w][q]=m; red[w][4+q]=s; }
  }
  __syncthreads();
  if (t<3)        ws[OFF_PSPA+bid*8+t]  =fmaxf(fmaxf(red[0][t],red[1][t]),fmaxf(red[2][t],red[3][t]));
  else if (t>=4&&t<7){
    const int q=t-4;
    ws[OFF_PSPA+bid*8+4+q]=red[0][4+q]+red[1][4+q]+red[2][4+q]+red[3][4+q];
  }
}

// ---- k_gram: G = g1^T g1 (64x64) + sum(g1) via MFMA, zero LDS, zero barriers ----
__global__ __launch_bounds__(512,2) void k_gram(
    const float* __restrict__ x,
    const float* __restrict__ w1, const float* __restrict__ b1,
    float* __restrict__ ws)
{
  const int t=threadIdx.x, w=t>>6, l=t&63, lg=l>>4, lr=l&15;
  const int bid=blockIdx.x;
  const int ti=w>>1, tj0=(w&1)*2, tj1=tj0+1;
  const float* A1=ws+OFF_A1; const float* C1=ws+OFF_C1;
  float wA[4], wB0[4], wB1[4];
  {
    const int fA=16*ti+lr;  const float aA=A1[fA];
    wA[0]=w1[fA]*aA;  wA[1]=w1[64+fA]*aA;  wA[2]=w1[128+fA]*aA;  wA[3]=b1[fA]*aA+C1[fA];
    const int f0=16*tj0+lr; const float a0=A1[f0];
    wB0[0]=w1[f0]*a0; wB0[1]=w1[64+f0]*a0; wB0[2]=w1[128+f0]*a0; wB0[3]=b1[f0]*a0+C1[f0];
    const int f1=16*tj1+lr; const float a1=A1[f1];
    wB1[0]=w1[f1]*a1; wB1[1]=w1[64+f1]*a1; wB1[2]=w1[128+f1]*a1; wB1[3]=b1[f1]*a1+C1[f1];
  }
  f32x4 acc0={0.f,0.f,0.f,0.f}, acc1={0.f,0.f,0.f,0.f};
  float s1=0.f;
  const float* xb = x + (size_t)bid*2048*3;
  #pragma unroll 1
  for (int step=0; step<64; ++step){
    x24_u xa;
    const float4* xp=(const float4*)(xb + (step*32+8*lg)*3);
    #pragma unroll
    for (int i=0;i<6;i++) xa.v4[i]=xp[i];
    float gA[8],gB0[8],gB1[8];
    #pragma unroll
    for (int j=0;j<8;j++){
      const float X=xa.f[3*j], Y=xa.f[3*j+1], Z=xa.f[3*j+2];
      gA[j] =fmaxf(fmaf(X,wA[0], fmaf(Y,wA[1], fmaf(Z,wA[2], wA[3]))),0.f);
      gB0[j]=fmaxf(fmaf(X,wB0[0],fmaf(Y,wB0[1],fmaf(Z,wB0[2],wB0[3]))),0.f);
      gB1[j]=fmaxf(fmaf(X,wB1[0],fmaf(Y,wB1[1],fmaf(Z,wB1[2],wB1[3]))),0.f);
    }
    frag_u fA,f0,f1;
    #pragma unroll
    for (int m=0;m<4;m++){
      fA.u[m]=cvt_pk_bf16(gA[2*m],gA[2*m+1]);
      f0.u[m]=cvt_pk_bf16(gB0[2*m],gB0[2*m+1]);
      f1.u[m]=cvt_pk_bf16(gB1[2*m],gB1[2*m+1]);
    }
    acc0=__builtin_amdgcn_mfma_f32_16x16x32_bf16(fA.v,f0.v,acc0,0,0,0);
    acc1=__builtin_amdgcn_mfma_f32_16x16x32_bf16(fA.v,f1.v,acc1,0,0,0);
    if (!(w&1)){
      #pragma unroll
      for (int j=0;j<8;j++) s1+=gA[j];
    }
  }
  #pragma unroll
  for (int q=0;q<4;q++){
    ws[OFF_PG + (size_t)((16*ti+4*lg+q)*64 + 16*tj0+lr)*512 + bid]=acc0[q];
    ws[OFF_PG + (size_t)((16*ti+4*lg+q)*64 + 16*tj1+lr)*512 + bid]=acc1[q];
  }
  if (!(w&1)){
    s1+=__shfl_xor(s1,16); s1+=__shfl_xor(s1,32);
    if (l<16) ws[OFF_PGS + (16*ti+lr)*512 + bid]=s1;
  }
}

// ---- k_redG: reduce G partials (+g1 sums) -> compact ----
__global__ __launch_bounds__(256) void k_redG(float* __restrict__ ws){
  __shared__ float red[256];
  const int t=threadIdx.x, blk=blockIdx.x;
  if (blk<64){
    const int e=blk*64+(t>>2), q=t&3;
    float s=0.f;
    const float* p=ws+OFF_PG+(size_t)e*512+q*128;
    #pragma unroll 8
    for (int i=0;i<128;i++) s+=p[i];
    red[t]=s; __syncthreads();
    if (q==0) ws[OFF_GC+e]=red[t]+red[t+1]+red[t+2]+red[t+3];
  } else {
    const int f=t>>2, q=t&3;
    float s=0.f;
    const float* p=ws+OFF_PGS+(size_t)f*512+q*128;
    #pragma unroll 8
    for (int i=0;i<128;i++) s+=p[i];
    red[t]=s; __syncthreads();
    if (q==0) ws[OFF_G1S+f]=red[t]+red[t+1]+red[t+2]+red[t+3];
  }
}

// ---- k_finB2: BN2 fold from G (128 blocks) + bucket centers (block 128) ----
__global__ __launch_bounds__(256) void k_finB2(
    const float* __restrict__ w2, const float* __restrict__ b2,
    const float* __restrict__ gm, const float* __restrict__ bt,
    float* __restrict__ ws){
  __shared__ float red[256];
  __shared__ float red2[64];
  const int t=threadIdx.x, j=blockIdx.x;
  if (j<128){
    float acc=0.f;
    #pragma unroll
    for (int p=0;p<16;p++){
      const int idx=p*256+t;
      const int r=idx>>6, c=idx&63;
      acc += w2[r*128+j]*ws[OFF_GC+r*64+c]*w2[c*128+j];
    }
    red[t]=acc;
    if (t<64) red2[t]=w2[t*128+j]*ws[OFF_G1S+t];
    __syncthreads();
    for (int s=128;s>0;s>>=1){ if (t<s) red[t]+=red[t+s]; __syncthreads(); }
    if (t<32) red2[t]+=red2[t+32];
    __syncthreads();
    if (t==0){
      float sw=0.f;
      #pragma unroll
      for (int i=0;i<32;i++) sw+=red2[i];
      const float i_n=1.f/NF;
      const float bj=b2[j];
      const float m=sw*i_n+bj;
      const float e2=(red[0]+2.f*bj*sw)*i_n+bj*bj;
      const float var=e2-m*m;
      const float a=gm[j]/sqrtf(var+1e-5f);
      ws[OFF_A2+j]=a; ws[OFF_C2+j]=bt[j]-m*a;
    }
  } else {
    if (t<176){
      const int b=t/NBK, k=t-b*NBK;
      float sx=0.f, sz=0.f, cn=0.f;
      #pragma unroll 8
      for (int blk=0;blk<32;blk++){
        const int p=OFF_PBKT+(b*32+blk)*36;
        sx+=ws[p+k]; sz+=ws[p+11+k]; cn+=ws[p+22+k];
      }
      const float d=fmaxf(cn,1.f);
      ws[OFF_CX+t]=sx/d; ws[OFF_CZ+t]=sz/d;
    }
  }
}

// ---- MFMA MLP pass (r8 proven body): 8 waves = 2 pt-groups x 4 feat-groups ----
// MODE 1 = h3 stats, 2 = pool. grid 1024, 8 iters of 128 pts, x-prefetch regs.
template<int MODE>
__global__ __launch_bounds__(512,2) void k_mlp(
    const float* __restrict__ x,
    const float* __restrict__ w1, const float* __restrict__ b1,
    const float* __restrict__ w2, const float* __restrict__ b2,
    const float* __restrict__ w3, const float* __restrict__ b3,
    float* __restrict__ ws)
{
  __shared__ short g1t[128*72];    // [pt][feat64], 144B rows
  __shared__ short g2t[128*136];   // [pt][feat128], 272B rows
  const int t=threadIdx.x, w=t>>6, l=t&63, lg=l>>4, lr=l&15;
  const int bid=blockIdx.x, b=bid>>6, chunk=bid&63;
  const int ptg=w&1, fgrp=w>>1;
  char* g1c=(char*)g1t; char* g2c=(char*)g2t;

  // layer1 folded weights: lane computes feats 8fg..8fg+7 for 2 pts
  const int fg=l&7, pj=(l>>3)&7;
  const float* a1=ws+OFF_A1; const float* c1=ws+OFF_C1;
  float w1f[3][8], b1f[8];
  #pragma unroll
  for (int i=0;i<8;i++){
    const int f=8*fg+i; const float a=a1[f];
    #pragma unroll
    for (int q=0;q<3;q++) w1f[q][i]=w1[q*64+f]*a;
    b1f[i]=b1[f]*a+c1[f];
  }

  // layer2 A-frags (W2^T, folded BN2): wave owns f2-tiles 2*fgrp+j
  s16x8 w2f[2][2]; float b2v[2][4];
  #pragma unroll
  for (int j=0;j<2;j++){
    const int col2=(2*fgrp+j)*16+lr;
    const float sc2=ws[OFF_A2+col2];
    #pragma unroll
    for (int kt=0;kt<2;kt++)
      #pragma unroll
      for (int i=0;i<8;i++)
        w2f[j][kt][i]=(short)bf16_bits(w2[(kt*32+8*lg+i)*128+col2]*sc2);
    #pragma unroll
    for (int r=0;r<4;r++){
      const int f2=(2*fgrp+j)*16+4*lg+r;
      b2v[j][r]=ws[OFF_A2+f2]*b2[f2]+ws[OFF_C2+f2];
    }
  }

  // layer3 A-frags (W3^T): wave owns f3-tiles 4*fgrp+j
  s16x8 w3f[4][4]; float b3v[4][4];
  #pragma unroll
  for (int j=0;j<4;j++){
    const int col3=(4*fgrp+j)*16+lr;
    const float sc3=(MODE==1)?1.f:ws[OFF_A3+col3];
    #pragma unroll
    for (int kt=0;kt<4;kt++)
      #pragma unroll
      for (int i=0;i<8;i++)
        w3f[j][kt][i]=(short)bf16_bits(w3[(kt*32+8*lg+i)*256+col3]*sc3);
    #pragma unroll
    for (int r=0;r<4;r++){
      const int f3=(4*fgrp+j)*16+4*lg+r;
      b3v[j][r]=(MODE==1)? b3[f3] : (ws[OFF_A3+f3]*b3[f3]+ws[OFF_C3+f3]);
    }
  }

  float aS[4][4], aQ[4][4];
  #pragma unroll
  for (int j=0;j<4;j++)
    #pragma unroll
    for (int r=0;r<4;r++){ aS[j][r]=(MODE==2)?-3.4e38f:0.f; aQ[j][r]=0.f; }

  const int base=b*N_+chunk*1024;
  const int ptl=16*w+2*pj;

  float c0[3], c1v[3], n0[3], n1[3];
  {
    const float* xp=&x[(size_t)(base+ptl)*3];
    #pragma unroll
    for (int q=0;q<3;q++){ c0[q]=xp[q]; c1v[q]=xp[3+q]; }
  }

  #pragma unroll 1
  for (int it=0; it<8; ++it){
    // layer1: 8 feats x 2 pts per lane -> g1
    #pragma unroll
    for (int s=0;s<2;s++){
      const float x0=s?c1v[0]:c0[0], x1v=s?c1v[1]:c0[1], x2=s?c1v[2]:c0[2];
      unsigned pk[4];
      #pragma unroll
      for (int i=0;i<4;i++){
        float v0=b1f[2*i], v1=b1f[2*i+1];
        v0=fmaf(x0,w1f[0][2*i],v0);  v1=fmaf(x0,w1f[0][2*i+1],v1);
        v0=fmaf(x1v,w1f[1][2*i],v0); v1=fmaf(x1v,w1f[1][2*i+1],v1);
        v0=fmaf(x2,w1f[2][2*i],v0);  v1=fmaf(x2,w1f[2][2*i+1],v1);
        pk[i]=cvt_pk_bf16(fmaxf(v0,0.f),fmaxf(v1,0.f));
      }
      *(int4*)(g1c + (ptl+s)*144 + fg*16) = make_int4(pk[0],pk[1],pk[2],pk[3]);
    }
    if (it<7){
      const float* xp=&x[(size_t)(base+(it+1)*128+ptl)*3];
      #pragma unroll
      for (int q=0;q<3;q++){ n0[q]=xp[q]; n1[q]=xp[3+q]; }
    }
    __syncthreads();
    // layer2: own pt-group (4 ptiles), own 2 f2-tiles; bias as C-in
    #pragma unroll
    for (int pt=0;pt<4;pt++){
      const int row=ptg*64+pt*16+lr;
      const s16x8 bf0=*(const s16x8*)(g1c + row*144 + lg*16);
      const s16x8 bf1=*(const s16x8*)(g1c + row*144 + 64 + lg*16);
      #pragma unroll
      for (int j=0;j<2;j++){
        f32x4 acc={b2v[j][0],b2v[j][1],b2v[j][2],b2v[j][3]};
        acc=__builtin_amdgcn_mfma_f32_16x16x32_bf16(w2f[j][0],bf0,acc,0,0,0);
        acc=__builtin_amdgcn_mfma_f32_16x16x32_bf16(w2f[j][1],bf1,acc,0,0,0);
        const unsigned lo=cvt_pk_bf16(fmaxf(acc[0],0.f),fmaxf(acc[1],0.f));
        const unsigned hi=cvt_pk_bf16(fmaxf(acc[2],0.f),fmaxf(acc[3],0.f));
        *(uint2*)(g2c + row*272 + fgrp*64 + j*32 + lg*8) = make_uint2(lo,hi);
      }
    }
    __syncthreads();
    // layer3: own pt-group, own 4 f3-tiles; bias as C-in
    #pragma unroll 1
    for (int pt=0;pt<4;pt++){
      const int row=ptg*64+pt*16+lr;
      const s16x8 bf0=*(const s16x8*)(g2c + row*272 + lg*16);
      const s16x8 bf1=*(const s16x8*)(g2c + row*272 + 64 + lg*16);
      const s16x8 bf2=*(const s16x8*)(g2c + row*272 + 128 + lg*16);
      const s16x8 bf3=*(const s16x8*)(g2c + row*272 + 192 + lg*16);
      #pragma unroll
      for (int j=0;j<4;j++){
        f32x4 a3={b3v[j][0],b3v[j][1],b3v[j][2],b3v[j][3]};
        a3=__builtin_amdgcn_mfma_f32_16x16x32_bf16(w3f[j][0],bf0,a3,0,0,0);
        a3=__builtin_amdgcn_mfma_f32_16x16x32_bf16(w3f[j][1],bf1,a3,0,0,0);
        a3=__builtin_amdgcn_mfma_f32_16x16x32_bf16(w3f[j][2],bf2,a3,0,0,0);
        a3=__builtin_amdgcn_mfma_f32_16x16x32_bf16(w3f[j][3],bf3,a3,0,0,0);
        #pragma unroll
        for (int r=0;r<4;r++){
          if (MODE==1){
            const float h=a3[r]; aS[j][r]+=h; aQ[j][r]=fmaf(h,h,aQ[j][r]);
          } else {
            const float g=fmaxf(a3[r],0.f);
            aS[j][r]=fmaxf(aS[j][r],g); aQ[j][r]+=g;
          }
        }
      }
    }
    #pragma unroll
    for (int q=0;q<3;q++){ c0[q]=n0[q]; c1v[q]=n1[q]; }
  }

  // flush: reduce over lr; coalesced [col][slot] layouts
  #pragma unroll
  for (int j=0;j<4;j++)
    #pragma unroll
    for (int r=0;r<4;r++){
      const int f3=(4*fgrp+j)*16+4*lg+r;
      if (MODE==1){
        float s=aS[j][r], q=aQ[j][r];
        #pragma unroll
        for (int m=1;m<16;m<<=1){ s+=__shfl_xor(s,m); q+=__shfl_xor(q,m); }
        if (lr==0){
          const int slot=bid*2+ptg;   // 0..2047
          ws[OFF_PH3 + (size_t)f3*2048 + slot]=s;
          ws[OFF_PH3 + (size_t)(256+f3)*2048 + slot]=q;
        }
      } else {
        float mxv=aS[j][r], s=aQ[j][r];
        #pragma unroll
        for (int m=1;m<16;m<<=1){ mxv=fmaxf(mxv,__shfl_xor(mxv,m)); s+=__shfl_xor(s,m); }
        if (lr==0){
          const int slot=chunk*2+ptg; // 0..127
          ws[OFF_PPOOL + (size_t)b*512*128 + (size_t)f3*128 + slot]=mxv;
          ws[OFF_PPOOL + (size_t)b*512*128 + (size_t)(256+f3)*128 + slot]=s;
        }
      }
    }
}

// ---- k_redH3: [col][2048 slots] -> compact ----
__global__ __launch_bounds__(256) void k_redH3(float* __restrict__ ws){
  __shared__ float red[256];
  const int t=threadIdx.x, blk=blockIdx.x;
  const int col=blk*16+(t>>4), part=t&15;
  float s=0.f;
  const float* p=ws+OFF_PH3+(size_t)col*2048+part*128;
  #pragma unroll 8
  for (int i=0;i<128;i++) s+=p[i];
  red[t]=s; __syncthreads();
  if (part==0){
    float r=0.f;
    #pragma unroll
    for (int i=0;i<16;i++) r+=red[(t&~15)+i];
    ws[OFF_H3C+col]=r;
  }
}

// ---- finC: BN3 fold from compact ----
__global__ void k_finC(const float* __restrict__ gm, const float* __restrict__ bt,
                       float* __restrict__ ws){
  const int t=threadIdx.x;
  if (t<256){
    const float i_n=1.f/NF;
    const float m=ws[OFF_H3C+t]*i_n;
    const float v=ws[OFF_H3C+256+t]*i_n-m*m;
    const float a=gm[t]/sqrtf(v+1e-5f);
    ws[OFF_A3+t]=a; ws[OFF_C3+t]=bt[t]-m*a;
  }
}

// ---- final: reduce pool, feat_cat(518) @ wp + bp, LayerNorm ----
__global__ __launch_bounds__(256) void k_final(
    const float* __restrict__ wp, const float* __restrict__ bp,
    const float* __restrict__ gln, const float* __restrict__ bln,
    float* __restrict__ out, const float* __restrict__ ws)
{
  __shared__ float feat[518];
  __shared__ float red[256];
  const int b=blockIdx.x, t=threadIdx.x;
  {
    float fm=-3.4e38f, fs=0.f;
    const float* pm =ws+OFF_PPOOL+(size_t)b*512*128+(size_t)t*128;
    const float* psu=ws+OFF_PPOOL+(size_t)b*512*128+(size_t)(256+t)*128;
    #pragma unroll 8
    for (int s=0;s<128;s++){ fm=fmaxf(fm,pm[s]); fs+=psu[s]; }
    feat[t]=fm; feat[NFEAT+t]=fs*(1.f/65536.f);
  }
  if (t<3){
    float fm=-3.4e38f, fs=0.f;
    #pragma unroll 4
    for (int blk=0;blk<32;blk++){
      const int p=OFF_PSPA+(b*32+blk)*8;
      fm=fmaxf(fm,ws[p+t]);
      fs+=ws[p+4+t];
    }
    feat[256+t]=fm; feat[NFEAT+256+t]=fs*(1.f/65536.f);
  }
  __syncthreads();
  float o0=bp[t], o1=bp[t+256];
  #pragma unroll 4
  for (int i=0;i<518;i++){
    const float f=feat[i];
    o0=fmaf(f, wp[i*512+t],     o0);
    o1=fmaf(f, wp[i*512+t+256], o1);
  }
  red[t]=o0+o1; __syncthreads();
  for (int s=128;s>0;s>>=1){ if (t<s) red[t]+=red[t+s]; __syncthreads(); }
  const float mu=red[0]*(1.f/512.f);
  __syncthreads();
  const float d0=o0-mu, d1=o1-mu;
  red[t]=d0*d0+d1*d1; __syncthreads();
  for (int s=128;s>0;s>>=1){ if (t<s) red[t]+=red[t+s]; __syncthreads(); }
  const float var=red[0]*(1.f/512.f);
  const float rs=1.f/sqrtf(var+1e-5f);
  out[b*512+t]     = d0*rs*gln[t]    +bln[t];
  out[b*512+t+256] = d1*rs*gln[t+256]+bln[t+256];
}

extern "C" void kernel_launch(void* const* d_in, const int* in_sizes, int n_in,
                              void* d_out, int out_size, void* d_ws, size_t ws_size,
                              hipStream_t stream)
{
  const float* x  =(const float*)d_in[0];
  const float* w1 =(const float*)d_in[1];
  const float* b1 =(const float*)d_in[2];
  const float* gm1=(const float*)d_in[3];
  const float* be1=(const float*)d_in[4];
  const float* w2 =(const float*)d_in[5];
  const float* b2 =(const float*)d_in[6];
  const float* gm2=(const float*)d_in[7];
  const float* be2=(const float*)d_in[8];
  const float* w3 =(const float*)d_in[9];
  const float* b3 =(const float*)d_in[10];
  const float* gm3=(const float*)d_in[11];
  const float* be3=(const float*)d_in[12];
  const float* wp =(const float*)d_in[13];
  const float* bp =(const float*)d_in[14];
  const float* gln=(const float*)d_in[15];
  const float* bln=(const float*)d_in[16];
  float* ws=(float*)d_ws;
  float* out=(float*)d_out;

  k_stream0<<<dim3(512), dim3(256),0,stream>>>(x,ws);
  k_finA   <<<dim3(1),   dim3(256),0,stream>>>(w1,b1,gm1,be1,ws);
  k_bucket <<<dim3(512), dim3(256),0,stream>>>(x,ws);
  k_gram   <<<dim3(512), dim3(512),0,stream>>>(x,w1,b1,ws);
  k_redG   <<<dim3(65),  dim3(256),0,stream>>>(ws);
  k_finB2  <<<dim3(129), dim3(256),0,stream>>>(w2,b2,gm2,be2,ws);
  k_spatial<<<dim3(512), dim3(256),0,stream>>>(x,ws);
  k_mlp<1> <<<dim3(1024),dim3(512),0,stream>>>(x,w1,b1,w2,b2,w3,b3,ws);
  k_redH3  <<<dim3(32),  dim3(256),0,stream>>>(ws);
  k_finC   <<<dim3(1),   dim3(256),0,stream>>>(gm3,be3,ws);
  k_mlp<2> <<<dim3(1024),dim3(512),0,stream>>>(x,w1,b1,w2,b2,w3,b3,ws);
  k_final  <<<dim3(16),  dim3(256),0,stream>>>(wp,bp,gln,bln,out,ws);
}